// Round 3
// baseline (134.150 us; speedup 1.0000x reference)
//
#include <hip/hip_runtime.h>
#include <math.h>

// Problem constants (fixed by setup_inputs)
namespace {
constexpr int BS = 16, Q = 900, CN = 91, T = 1600;
constexpr int N  = BS * Q;              // 14400 queries total
constexpr float kALPHA = 0.25f;
constexpr float kEPS   = 1e-8f;

constexpr int TT = 320;   // t-tile == blockDim.x (1600 = 5*320, no tail)
constexpr int NT = 32;    // n rows per block

// ---------------------------------------------------------------------------
// Fused cost kernel: out[n][t] = L1(cxcywh) + focal_class(tl) + (1 - iou - u/aC)
//
// Block: 320 threads, each owns one t (t-data in registers); loops NT=32
// n-rows. The focal class-cost rows for this block's 32 queries are computed
// from raw logits directly into LDS during staging (no prologue kernel, no
// workspace). Logits are 5.2 MB -> fully L3-resident across the 5x re-read.
// ---------------------------------------------------------------------------
__global__ __launch_bounds__(TT) void k_cost(
    const float*  __restrict__ logits,   // [N*CN]
    const float4* __restrict__ pboxes,   // [N] raw cxcywh
    const float4* __restrict__ tboxes,   // [T] raw cxcywh
    const int*    __restrict__ tlab,     // [T]
    float*        __restrict__ out)      // [N*T]
{
    __shared__ float sK[NT * CN];        // 11.6 KB: class-cost rows for n0..n0+31

    const int tid = threadIdx.x;
    const int t0  = blockIdx.x * TT;
    const int n0  = blockIdx.y * NT;

    // ---- per-thread target data, registers only ----
    const float4 tb = tboxes[t0 + tid];
    const int    tl = tlab[t0 + tid];
    const float tcx = tb.x, tcy = tb.y, tw = tb.z, th = tb.w;
    const float tx0 = tcx - 0.5f * tw, ty0 = tcy - 0.5f * th;
    const float tx1 = tcx + 0.5f * tw, ty1 = tcy + 0.5f * th;
    const float tar = (tx1 - tx0) * (ty1 - ty0);

    // ---- stage focal class-cost rows: K[n][c] = pos - neg ----
    // contiguous coalesced logit reads; 2912/320 ~ 9.1 iters/thread
    for (int i = tid; i < NT * CN; i += TT) {
        float x  = logits[n0 * CN + i];
        float p  = 1.0f / (1.0f + expf(-x));          // sigmoid
        float om = 1.0f - p;
        float pos = kALPHA          * om * om * (-logf(p  + kEPS));
        float neg = (1.0f - kALPHA) * p  * p  * (-logf(om + kEPS));
        sK[i] = pos - neg;
    }
    __syncthreads();

    float* outp = out + t0 + tid;

    #pragma unroll 4
    for (int i = 0; i < NT; ++i) {
        const int n = n0 + i;
        // wave-uniform loads (n uniform across block)
        const float4 braw = pboxes[n];
        const float  cls  = sK[i * CN + tl];

        // n-box xyxy + area (6 VALU, wave-uniform values)
        const float bx0 = braw.x - 0.5f * braw.z, by0 = braw.y - 0.5f * braw.w;
        const float bx1 = braw.x + 0.5f * braw.z, by1 = braw.y + 0.5f * braw.w;
        const float aA  = (bx1 - bx0) * (by1 - by0);

        // L1 over raw cxcywh
        float l1 = fabsf(braw.x - tcx) + fabsf(braw.y - tcy)
                 + fabsf(braw.z - tw ) + fabsf(braw.w - th );

        // intersection
        float ix0 = fmaxf(bx0, tx0), iy0 = fmaxf(by0, ty0);
        float ix1 = fminf(bx1, tx1), iy1 = fminf(by1, ty1);
        float iw  = fmaxf(ix1 - ix0, 0.0f), ih = fmaxf(iy1 - iy0, 0.0f);
        float inter = iw * ih;
        float uni   = aA + tar - inter;

        // enclosing box
        float cx0 = fminf(bx0, tx0), cy0 = fminf(by0, ty0);
        float cx1 = fmaxf(bx1, tx1), cy1 = fmaxf(by1, ty1);
        float aC  = (cx1 - cx0) * (cy1 - cy0);

        // -giou = 1 - inter/union - union/areaC   (v_rcp_f32: ~1 ulp)
        float giou_cost = 1.0f - inter * __builtin_amdgcn_rcpf(uni)
                               - uni   * __builtin_amdgcn_rcpf(aC);

        outp[n * T] = l1 + cls + giou_cost;
    }
}
} // namespace

extern "C" void kernel_launch(void* const* d_in, const int* in_sizes, int n_in,
                              void* d_out, int out_size, void* d_ws, size_t ws_size,
                              hipStream_t stream)
{
    const float*  logits = (const float*) d_in[0];   // [16,900,91]
    const float4* pboxes = (const float4*)d_in[1];   // [16,900,4]
    const int*    tlab   = (const int*)   d_in[2];   // [1600]
    const float4* tboxes = (const float4*)d_in[3];   // [1600,4]
    float*        out    = (float*)d_out;            // [16,900,1600]

    dim3 grid(T / TT, N / NT);   // 5 x 450
    hipLaunchKernelGGL(k_cost, grid, dim3(TT), 0, stream,
                       logits, pboxes, tboxes, tlab, out);
}